// Round 11
// baseline (417.060 us; speedup 1.0000x reference)
//
#include <hip/hip_runtime.h>
#include <hip/hip_bf16.h>

#define DIM 256
#define HEADS 8
#define DHEAD 32
#define SEQ 2048
#define BATCH 2
#define NROWS (BATCH*SEQ)    // 4096 total rows
#define EPS 1e-5f

typedef __attribute__((ext_vector_type(8))) short bf16x8;   // MFMA A/B frag (4 VGPRs)
typedef __attribute__((ext_vector_type(4))) float f32x4;    // MFMA C/D frag

__device__ __forceinline__ unsigned short f2b(float f) {
    __hip_bfloat16 h = __float2bfloat16(f);
    return *reinterpret_cast<unsigned short*>(&h);
}

__device__ __forceinline__ bf16x8 cvt8(float4 a, float4 b) {
    bf16x8 r;
    r[0] = (short)f2b(a.x); r[1] = (short)f2b(a.y);
    r[2] = (short)f2b(a.z); r[3] = (short)f2b(a.w);
    r[4] = (short)f2b(b.x); r[5] = (short)f2b(b.y);
    r[6] = (short)f2b(b.z); r[7] = (short)f2b(b.w);
    return r;
}

// ---------------------------------------------------------------------------
// tprep256 (exact wprep clone at 256x256): WT[n][k] = bf16(W[k][n]).
// ---------------------------------------------------------------------------
__global__ void tprep256(const float* __restrict__ W,
                         unsigned short* __restrict__ WT) {
    const int tid = blockIdx.x * 256 + threadIdx.x;
    const int stride = gridDim.x * 256;
    for (int i = tid; i < 256 * 256; i += stride) {
        int n = i >> 8, k = i & 255;
        WT[i] = f2b(W[k * 256 + n]);
    }
}

// ---------------------------------------------------------------------------
// qkv_gemm (UNDER TEST): out = bf16((x @ W) * scale), row-major store.
// Strict wo_ln_mfma GEMM body at K=256 (A fp32+cvt8 in-loop, acc[4], nt<4).
// ---------------------------------------------------------------------------
__global__ __launch_bounds__(256) void qkv_gemm(
        const float* __restrict__ x,
        const unsigned short* __restrict__ WT,   // [256][256] bf16
        unsigned short* __restrict__ outp,
        float scale) {
    const int t    = threadIdx.x;
    const int w    = t >> 6;
    const int lane = t & 63;
    const int quad = lane >> 4;
    const int c16  = lane & 15;
    const int r0   = blockIdx.x * 16;

    const float* arow = x + (size_t)(r0 + c16) * 256 + quad * 8;

    f32x4 acc[4];
#pragma unroll
    for (int nt = 0; nt < 4; nt++) acc[nt] = (f32x4){0.f, 0.f, 0.f, 0.f};

#pragma unroll 2
    for (int kc = 0; kc < 256; kc += 32) {
        float4 a0 = *(const float4*)(arow + kc);
        float4 a1 = *(const float4*)(arow + kc + 4);
        bf16x8 afg = cvt8(a0, a1);
#pragma unroll
        for (int nt = 0; nt < 4; nt++) {
            const int n0 = w * 64 + nt * 16;
            bf16x8 bfg = *(const bf16x8*)&WT[(size_t)(n0 + c16) * 256 + kc + quad * 8];
            acc[nt] = __builtin_amdgcn_mfma_f32_16x16x32_bf16(afg, bfg, acc[nt], 0, 0, 0);
        }
    }

#pragma unroll
    for (int reg = 0; reg < 4; reg++) {
        const int row = r0 + quad * 4 + reg;
#pragma unroll
        for (int nt = 0; nt < 4; nt++) {
            const int col = w * 64 + nt * 16 + c16;
            outp[(size_t)row * 256 + col] = f2b(acc[nt][reg] * scale);
        }
    }
}

// ---------------------------------------------------------------------------
// qkv_v_gemm (UNDER TEST): v = x @ Wv, stored TRANSPOSED per batch
// (round-4-validated formula: vt[(b*256+col)*2048 + key]).
// ---------------------------------------------------------------------------
__global__ __launch_bounds__(256) void qkv_v_gemm(
        const float* __restrict__ x,
        const unsigned short* __restrict__ WT,   // [256][256] bf16
        unsigned short* __restrict__ vtb) {
    const int t    = threadIdx.x;
    const int w    = t >> 6;
    const int lane = t & 63;
    const int quad = lane >> 4;
    const int c16  = lane & 15;
    const int r0   = blockIdx.x * 16;

    const float* arow = x + (size_t)(r0 + c16) * 256 + quad * 8;

    f32x4 acc[4];
#pragma unroll
    for (int nt = 0; nt < 4; nt++) acc[nt] = (f32x4){0.f, 0.f, 0.f, 0.f};

#pragma unroll 2
    for (int kc = 0; kc < 256; kc += 32) {
        float4 a0 = *(const float4*)(arow + kc);
        float4 a1 = *(const float4*)(arow + kc + 4);
        bf16x8 afg = cvt8(a0, a1);
#pragma unroll
        for (int nt = 0; nt < 4; nt++) {
            const int n0 = w * 64 + nt * 16;
            bf16x8 bfg = *(const bf16x8*)&WT[(size_t)(n0 + c16) * 256 + kc + quad * 8];
            acc[nt] = __builtin_amdgcn_mfma_f32_16x16x32_bf16(afg, bfg, acc[nt], 0, 0, 0);
        }
    }

#pragma unroll
    for (int reg = 0; reg < 4; reg++) {
        const int row = r0 + quad * 4 + reg;
        const int bb  = row >> 11;
        const int key = row & 2047;
#pragma unroll
        for (int nt = 0; nt < 4; nt++) {
            const int col = w * 64 + nt * 16 + c16;
            vtb[((size_t)(bb * 256 + col)) * SEQ + key] = f2b(acc[nt][reg]);
        }
    }
}

// ---------------------------------------------------------------------------
// Kernel 2 (VERBATIM round 7, passed): MFMA flash attention, fp32 attout.
// ---------------------------------------------------------------------------
__global__ __launch_bounds__(256, 2) void attn_mfma(
        const unsigned short* __restrict__ qb,
        const unsigned short* __restrict__ kb,
        const unsigned short* __restrict__ vtb,
        float* __restrict__ attout) {
    __shared__ __align__(16) unsigned short Ks[32][40];
    __shared__ __align__(16) unsigned short Vs[256][40];
    __shared__ __align__(16) unsigned short Ps[4][16][40];

    const int t    = threadIdx.x;
    const int w    = t >> 6;
    const int lane = t & 63;
    const int quad = lane >> 4;
    const int c16  = lane & 15;
    const int h    = blockIdx.y;
    const int b    = blockIdx.z;
    const int i0   = blockIdx.x * 64 + w * 16;

    const size_t qk_head = ((size_t)b * SEQ) * DIM + h * DHEAD;

    bf16x8 qf = *(const bf16x8*)&qb[qk_head + (size_t)(i0 + c16) * DIM + quad * 8];

    f32x4 acc[16];
#pragma unroll
    for (int nt = 0; nt < 16; nt++) acc[nt] = (f32x4){0.f, 0.f, 0.f, 0.f};
    float mrow[4] = {-1e30f, -1e30f, -1e30f, -1e30f};
    float lrow[4] = {0.f, 0.f, 0.f, 0.f};
    const f32x4 zero = (f32x4){0.f, 0.f, 0.f, 0.f};

    for (int jt = 0; jt < SEQ / 32; jt++) {
        const int j0 = jt * 32;
        __syncthreads();
        if (t < 128) {
            int key = t >> 2, part = t & 3;
            *(bf16x8*)&Ks[key][part * 8] =
                *(const bf16x8*)&kb[qk_head + (size_t)(j0 + key) * DIM + part * 8];
        }
        {
            const size_t vbase = ((size_t)b * 256) * SEQ + j0;
#pragma unroll
            for (int i = 0; i < 4; i++) {
                int id = t + i * 256;
                int cc = id >> 2, part = id & 3;
                *(bf16x8*)&Vs[cc][part * 8] =
                    *(const bf16x8*)&vtb[vbase + (size_t)cc * SEQ + part * 8];
            }
        }
        __syncthreads();

        bf16x8 kf0 = *(const bf16x8*)&Ks[c16][quad * 8];
        bf16x8 kf1 = *(const bf16x8*)&Ks[16 + c16][quad * 8];
        f32x4 s0 = __builtin_amdgcn_mfma_f32_16x16x32_bf16(qf, kf0, zero, 0, 0, 0);
        f32x4 s1 = __builtin_amdgcn_mfma_f32_16x16x32_bf16(qf, kf1, zero, 0, 0, 0);

        float alpha[4];
#pragma unroll
        for (int reg = 0; reg < 4; reg++) {
            float mx = fmaxf(s0[reg], s1[reg]);
#pragma unroll
            for (int m = 1; m <= 8; m <<= 1) mx = fmaxf(mx, __shfl_xor(mx, m, 64));
            float mn = fmaxf(mrow[reg], mx);
            alpha[reg] = __expf(mrow[reg] - mn);
            mrow[reg] = mn;
            float p0 = __expf(s0[reg] - mn);
            float p1 = __expf(s1[reg] - mn);
            float ps = p0 + p1;
#pragma unroll
            for (int m = 1; m <= 8; m <<= 1) ps += __shfl_xor(ps, m, 64);
            lrow[reg] = lrow[reg] * alpha[reg] + ps;
            Ps[w][quad * 4 + reg][c16]      = f2b(p0);
            Ps[w][quad * 4 + reg][16 + c16] = f2b(p1);
        }
#pragma unroll
        for (int nt = 0; nt < 16; nt++) {
            acc[nt][0] *= alpha[0];
            acc[nt][1] *= alpha[1];
            acc[nt][2] *= alpha[2];
            acc[nt][3] *= alpha[3];
        }
        __builtin_amdgcn_s_waitcnt(0);

        bf16x8 pf = *(const bf16x8*)&Ps[w][c16][quad * 8];
#pragma unroll
        for (int nt = 0; nt < 16; nt++) {
            bf16x8 vf = *(const bf16x8*)&Vs[nt * 16 + c16][quad * 8];
            acc[nt] = __builtin_amdgcn_mfma_f32_16x16x32_bf16(pf, vf, acc[nt], 0, 0, 0);
        }
    }

#pragma unroll
    for (int reg = 0; reg < 4; reg++) {
        float inv = 1.f / lrow[reg];
        int row = i0 + quad * 4 + reg;
#pragma unroll
        for (int nt = 0; nt < 16; nt++) {
            attout[((size_t)b * SEQ + row) * (size_t)(HEADS * DIM) + h * DIM + nt * 16 + c16] =
                acc[nt][reg] * inv;
        }
    }
}

// ---------------------------------------------------------------------------
// Kernel 3 (VERBATIM round 7, passed): WoT[n][k] = bf16(Wo[k][n]).  1D grid.
// ---------------------------------------------------------------------------
__global__ void wprep(const float* __restrict__ Wo,
                      unsigned short* __restrict__ WoT) {
    const int tid = blockIdx.x * 256 + threadIdx.x;
    const int stride = gridDim.x * 256;
    for (int i = tid; i < 256 * 2048; i += stride) {
        int n = i >> 11, k = i & 2047;
        WoT[i] = f2b(Wo[k * 256 + n]);
    }
}

// ---------------------------------------------------------------------------
// Kernel 4 (VERBATIM round 7, passed): MFMA wo + residual + LN1.
// ---------------------------------------------------------------------------
__global__ __launch_bounds__(256) void wo_ln_mfma(
        const float* __restrict__ attout,        // [4096][2048] fp32
        const unsigned short* __restrict__ WoT,  // [256][2048] bf16
        const float* __restrict__ x,
        const float* __restrict__ gamma1,
        float* __restrict__ ln1) {
    __shared__ float Ct[16][264];
    __shared__ float ps1[16][16], ps2[16][16];
    __shared__ float mu[16], rsd[16];

    const int t    = threadIdx.x;
    const int w    = t >> 6;
    const int lane = t & 63;
    const int quad = lane >> 4;
    const int c16  = lane & 15;
    const int r0   = blockIdx.x * 16;

    const float* arow = attout + (size_t)(r0 + c16) * 2048 + quad * 8;

    f32x4 acc[4];
#pragma unroll
    for (int nt = 0; nt < 4; nt++) acc[nt] = (f32x4){0.f, 0.f, 0.f, 0.f};

#pragma unroll 2
    for (int kc = 0; kc < 2048; kc += 32) {
        float4 a0 = *(const float4*)(arow + kc);
        float4 a1 = *(const float4*)(arow + kc + 4);
        bf16x8 afg = cvt8(a0, a1);
#pragma unroll
        for (int nt = 0; nt < 4; nt++) {
            const int n0 = w * 64 + nt * 16;
            bf16x8 bfg = *(const bf16x8*)&WoT[(size_t)(n0 + c16) * 2048 + kc + quad * 8];
            acc[nt] = __builtin_amdgcn_mfma_f32_16x16x32_bf16(afg, bfg, acc[nt], 0, 0, 0);
        }
    }

#pragma unroll
    for (int reg = 0; reg < 4; reg++) {
        const int row = quad * 4 + reg;
#pragma unroll
        for (int nt = 0; nt < 4; nt++) {
            const int col = w * 64 + nt * 16 + c16;
            Ct[row][col] = acc[nt][reg] + x[(size_t)(r0 + row) * 256 + col];
        }
    }
    __syncthreads();
    {
        const int row = t >> 4, seg = t & 15;
        float s = 0.f, s2 = 0.f;
#pragma unroll
        for (int j = 0; j < 16; j++) { float v = Ct[row][seg * 16 + j]; s += v; s2 += v * v; }
        ps1[row][seg] = s; ps2[row][seg] = s2;
    }
    __syncthreads();
    if (t < 16) {
        float s = 0.f, s2 = 0.f;
#pragma unroll
        for (int j = 0; j < 16; j++) { s += ps1[t][j]; s2 += ps2[t][j]; }
        float m = s * (1.0f / 256.0f);
        float var = s2 * (1.0f / 256.0f) - m * m;
        mu[t] = m; rsd[t] = rsqrtf(var + EPS);
    }
    __syncthreads();
    const float g = gamma1[t];
#pragma unroll
    for (int r = 0; r < 16; r++)
        ln1[(size_t)(r0 + r) * 256 + t] = (Ct[r][t] - mu[r]) * rsd[r] * g;
}

// ---------------------------------------------------------------------------
// Kernel 5 (VERBATIM round 7, passed): fp32 FFN + LN2.
// ---------------------------------------------------------------------------
__global__ void ffn_ln(const float* __restrict__ ln1,
                       const float* __restrict__ Wf1,
                       const float* __restrict__ Wf2,
                       const float* __restrict__ gamma2,
                       float* __restrict__ out) {
    __shared__ float xs[16][257];
    __shared__ float hs[16][512];
    __shared__ float mu[16], rs[16];
    const int t  = threadIdx.x;
    const int r0 = blockIdx.x * 16;

    for (int idx = t; idx < 16 * DIM; idx += 256) {
        int r = idx >> 8, c = idx & 255;
        xs[r][c] = ln1[(size_t)(r0 + r) * DIM + c];
    }
    __syncthreads();

    float h0[16], h1[16];
#pragma unroll
    for (int r = 0; r < 16; r++) { h0[r] = 0.f; h1[r] = 0.f; }
    for (int kk = 0; kk < DIM; kk++) {
        float w0 = Wf1[(size_t)kk * 512 + t];
        float w1 = Wf1[(size_t)kk * 512 + t + 256];
#pragma unroll
        for (int r = 0; r < 16; r++) {
            float xv = xs[r][kk];
            h0[r] += xv * w0;
            h1[r] += xv * w1;
        }
    }
#pragma unroll
    for (int r = 0; r < 16; r++) {
        hs[r][t]       = fmaxf(h0[r], 0.f);
        hs[r][t + 256] = fmaxf(h1[r], 0.f);
    }
    __syncthreads();

    float acc[16];
#pragma unroll
    for (int r = 0; r < 16; r++) acc[r] = 0.f;
    for (int kk = 0; kk < 512; kk++) {
        float w = Wf2[(size_t)kk * DIM + t];
#pragma unroll
        for (int r = 0; r < 16; r++) acc[r] += hs[r][kk] * w;  // hs broadcast
    }

#pragma unroll
    for (int r = 0; r < 16; r++) xs[r][t] = acc[r];
    __syncthreads();
    if (t < 16) {
        float s = 0.f, s2 = 0.f;
        for (int c = 0; c < DIM; c++) { float vv = xs[t][c]; s += vv; s2 += vv * vv; }
        float m = s * (1.0f / DIM);
        float var = s2 * (1.0f / DIM) - m * m;
        mu[t] = m;
        rs[t] = rsqrtf(var + EPS);
    }
    __syncthreads();
    const float g = gamma2[t];
#pragma unroll
    for (int r = 0; r < 16; r++) {
        out[(size_t)(r0 + r) * DIM + t] = (xs[r][t] - mu[r]) * rs[r] * g;
    }
}

// ---------------------------------------------------------------------------
extern "C" void kernel_launch(void* const* d_in, const int* in_sizes, int n_in,
                              void* d_out, int out_size, void* d_ws, size_t ws_size,
                              hipStream_t stream) {
    const float* x      = (const float*)d_in[0];
    const float* Wq     = (const float*)d_in[1];
    const float* Wk     = (const float*)d_in[2];
    const float* Wv     = (const float*)d_in[3];
    const float* Wo     = (const float*)d_in[4];
    const float* Wf1    = (const float*)d_in[5];
    const float* Wf2    = (const float*)d_in[6];
    const float* gamma1 = (const float*)d_in[7];
    const float* gamma2 = (const float*)d_in[8];
    float* out = (float*)d_out;

    // workspace layout: round-7 layout verbatim, W{q,k,v}T appended.
    char* base = (char*)d_ws;
    unsigned short* qb  = (unsigned short*)(base);              // 2 MB
    unsigned short* kb  = (unsigned short*)(base +  2097152);   // 2 MB
    unsigned short* vtb = (unsigned short*)(base +  4194304);   // 2 MB
    float* attout       = (float*)         (base +  6291456);   // 32 MB
    float* ln1          = (float*)         (base + 39845888);   // 4 MB
    unsigned short* WoT = (unsigned short*)(base + 44040192);   // 1 MB
    unsigned short* WqT = (unsigned short*)(base + 45088768);   // 128 KB
    unsigned short* WkT = (unsigned short*)(base + 45219840);   // 128 KB
    unsigned short* WvT = (unsigned short*)(base + 45350912);   // 128 KB -> ends 45,481,984

    const float scale = 0.17677669529663687f;  // 1/sqrt(32)

    tprep256<<<64, 256, 0, stream>>>(Wq, WqT);
    tprep256<<<64, 256, 0, stream>>>(Wk, WkT);
    tprep256<<<64, 256, 0, stream>>>(Wv, WvT);
    wprep<<<64, 256, 0, stream>>>(Wo, WoT);
    qkv_gemm<<<NROWS / 16, 256, 0, stream>>>(x, WqT, qb, scale);
    qkv_gemm<<<NROWS / 16, 256, 0, stream>>>(x, WkT, kb, 1.0f);
    qkv_v_gemm<<<NROWS / 16, 256, 0, stream>>>(x, WvT, vtb);
    attn_mfma<<<dim3(SEQ / 64, HEADS, BATCH), 256, 0, stream>>>(qb, kb, vtb, attout);
    wo_ln_mfma<<<NROWS / 16, 256, 0, stream>>>(attout, WoT, x, gamma1, ln1);
    ffn_ln<<<NROWS / 16, 256, 0, stream>>>(ln1, Wf1, Wf2, gamma2, out);
}